// Round 1
// baseline (390.157 us; speedup 1.0000x reference)
//
#include <hip/hip_runtime.h>

typedef _Float16 f16;
typedef f16 f16x4 __attribute__((ext_vector_type(4)));
typedef f16 f16x8 __attribute__((ext_vector_type(8)));
typedef float f32x4 __attribute__((ext_vector_type(4)));

#define LDQ 68                 // qkvT row stride in halfs (64 tokens + 4 pad)
#define QKV_OFF 32768          // xw buffer: 64 rows * 512 B (swizzled, no pad)
#define QKV_BYTES (768 * LDQ * 2)        // 104448
#define SPART_OFF (QKV_OFF + QKV_BYTES)  // 137216
#define SPART_BYTES (32 * 64 * 4)        // 8192
#define SMEM_TOTAL (SPART_OFF + SPART_BYTES)  // 145408

// fp32 -> fp16 weight conversion (w_qkv 768x256, w_proj 256x256)
__global__ __launch_bounds__(256) void cvt_weights_k(
    const float* __restrict__ wq, const float* __restrict__ wp,
    f16* __restrict__ wq_h, f16* __restrict__ wp_h) {
  int idx = blockIdx.x * 256 + threadIdx.x;  // grid covers 262144
  if (idx < 768 * 256) {
    wq_h[idx] = (f16)wq[idx];
  } else {
    int r = idx - 768 * 256;
    wp_h[r] = (f16)wp[r];
  }
}

// XOR-swizzled address into the xw/out2 LDS tile: row stride 512 B,
// byte^=((row&7)<<4) makes ds_read_b128 column-slices bank-conflict-free (T2).
__device__ __forceinline__ char* xwp(char* s, int row, int colbyte) {
  return s + row * 512 + (colbyte ^ ((row & 7) << 4));
}

__global__ __launch_bounds__(512) void win_attn_k(
    const float* __restrict__ x, const f16* __restrict__ wq_h,
    const f16* __restrict__ wp_h, float* __restrict__ out) {
  extern __shared__ char smem[];
  f16* qkvT = (f16*)(smem + QKV_OFF);     // [768 features][68] (64 tokens + pad)
  float* spart = (float*)(smem + SPART_OFF);  // [dh*4+h][g][64 tokens] f32

  const int tid = threadIdx.x;
  const int wi = blockIdx.x;                 // window id: ((b*8+i)*8+j)*8+k
  const int kw = wi & 7, jw = (wi >> 3) & 7, iw = (wi >> 6) & 7, bw = wi >> 9;
  const float* xb = x + (size_t)bw * 8388608 + iw * 4096 + jw * 128 + kw * 4;

  // ---- Phase 1: stage xw (64 tokens x 256 "c2") = reshape of xin[c][pos] ----
  // xw[t][c2] = x[b, c=t*4+(c2>>6), z=i*4+((c2>>4)&3), y=j*4+((c2>>2)&3), x=k*4+(c2&3)]
  // flat(t,c2) == flat(c,pos): store row t=c>>2, colbyte = ((c&3)*64 + a*16 + b*4)*2.
#pragma unroll
  for (int it = 0; it < 8; ++it) {
    int idx = it * 512 + tid;  // 0..4095 : (c, a, bb)
    int c = idx >> 4, a = (idx >> 2) & 3, bb = idx & 3;
    float4 v = *(const float4*)(xb + (size_t)c * 32768 + a * 1024 + bb * 32);
    f16x4 h;
    h[0] = (f16)v.x; h[1] = (f16)v.y; h[2] = (f16)v.z; h[3] = (f16)v.w;
    *(f16x4*)xwp(smem, c >> 2, (c & 3) * 128 + a * 32 + bb * 8) = h;
  }
  __syncthreads();

  const int wv = tid >> 6, lane = tid & 63;
  const int lcol = lane & 15, lq = lane >> 4;

  // ---- Phase 2: GEMM1 qkv[64x768] = xw[64x256] @ w_qkv^T, wave = 96-col slice ----
  for (int nc = 0; nc < 2; ++nc) {
    const int ncb = wv * 96 + nc * 48;
    f32x4 acc[4][3] = {};
    for (int kt = 0; kt < 8; ++kt) {
      f16x8 afr[4];
#pragma unroll
      for (int mt = 0; mt < 4; ++mt) {
        int row = mt * 16 + lcol;
        afr[mt] = *(const f16x8*)xwp(smem, row, kt * 64 + lq * 16);
      }
#pragma unroll
      for (int nt = 0; nt < 3; ++nt) {
        f16x8 bfr = *(const f16x8*)(wq_h + (ncb + nt * 16 + lcol) * 256 + kt * 32 + lq * 8);
#pragma unroll
        for (int mt = 0; mt < 4; ++mt)
          acc[mt][nt] = __builtin_amdgcn_mfma_f32_16x16x32_f16(afr[mt], bfr, acc[mt][nt], 0, 0, 0);
      }
    }
    // D layout: col = lane&15 (feature), row = lq*4 + r (token). Store transposed:
    // qkvT[feature][token], 4 consecutive tokens per lane -> one 8B write.
#pragma unroll
    for (int mt = 0; mt < 4; ++mt)
#pragma unroll
      for (int nt = 0; nt < 3; ++nt) {
        f16x4 hv;
        hv[0] = (f16)acc[mt][nt][0]; hv[1] = (f16)acc[mt][nt][1];
        hv[2] = (f16)acc[mt][nt][2]; hv[3] = (f16)acc[mt][nt][3];
        *(f16x4*)(qkvT + (ncb + nt * 16 + lcol) * LDQ + mt * 16 + lq * 4) = hv;
      }
  }
  __syncthreads();

  // ---- Phase 3a: S partials. wave = (h = wv&3, dh = wv>>2), lane = token t ----
  {
    const int h = wv & 3, dh = wv >> 2, t = lane;
    float qreg[32];
#pragma unroll
    for (int dd = 0; dd < 32; ++dd)
      qreg[dd] = (float)qkvT[(h * 64 + dh * 32 + dd) * LDQ + t];
#pragma unroll
    for (int g = 0; g < 4; ++g) {
      float s = 0.f;
#pragma unroll
      for (int dd = 0; dd < 32; ++dd)
        s += qreg[dd] * (float)qkvT[(256 + g * 64 + dh * 32 + dd) * LDQ + t];
      spart[((dh * 4 + h) * 4 + g) * 64 + t] = s;
    }
  }
  __syncthreads();

  // ---- Phase 3b: clip+softmax over g (4 heads), then O = P @ V (d-half per wave) ----
  {
    const int h = wv & 3, dh = wv >> 2, t = lane;
    float P[4];
    float mx = -1e30f;
#pragma unroll
    for (int g = 0; g < 4; ++g) {
      float s = spart[(h * 4 + g) * 64 + t] + spart[((4 + h) * 4 + g) * 64 + t];
      s *= 0.125f;                       // SCALE = 64^-0.5
      s = fminf(fmaxf(s, -10.f), 10.f);  // clip BEFORE softmax (reference order)
      P[g] = s;
      mx = fmaxf(mx, s);
    }
    float sum = 0.f;
#pragma unroll
    for (int g = 0; g < 4; ++g) { P[g] = __expf(P[g] - mx); sum += P[g]; }
    float inv = 1.f / sum;
#pragma unroll
    for (int g = 0; g < 4; ++g) P[g] *= inv;

    // out2[t2][c2]: t2 = h*16 + (t>>2), c2 = (t&3)*64 + d  (reuse xw LDS buffer)
    const int row = h * 16 + (t >> 2);
    const int cb0 = (t & 3) * 128 + dh * 64;
#pragma unroll
    for (int db = 0; db < 32; db += 8) {
      f16x8 hv;
#pragma unroll
      for (int u = 0; u < 8; ++u) {
        int d = dh * 32 + db + u;
        float o = 0.f;
#pragma unroll
        for (int g = 0; g < 4; ++g)
          o += P[g] * (float)qkvT[(512 + g * 64 + d) * LDQ + t];
        hv[u] = (f16)o;
      }
      *(f16x8*)xwp(smem, row, cb0 + db * 2) = hv;
    }
  }
  __syncthreads();

  // ---- Phase 4: GEMM2 final[64x256] = out2 @ w_proj^T, wave = 32-col slice ----
  {
    f32x4 acc[4][2] = {};
    for (int kt = 0; kt < 8; ++kt) {
      f16x8 afr[4];
#pragma unroll
      for (int mt = 0; mt < 4; ++mt)
        afr[mt] = *(const f16x8*)xwp(smem, mt * 16 + lcol, kt * 64 + lq * 16);
#pragma unroll
      for (int nt = 0; nt < 2; ++nt) {
        f16x8 bfr = *(const f16x8*)(wp_h + (wv * 32 + nt * 16 + lcol) * 256 + kt * 32 + lq * 8);
#pragma unroll
        for (int mt = 0; mt < 4; ++mt)
          acc[mt][nt] = __builtin_amdgcn_mfma_f32_16x16x32_f16(afr[mt], bfr, acc[mt][nt], 0, 0, 0);
      }
    }
    // t2 = mt*16 + lq*4 + r -> (a'=mt, b'=lq, c'=r): out[b][c3][i*4+a'][j*4+b'][k*4+c']
    float* ob = out + (size_t)bw * 8388608 + iw * 4096 + jw * 128 + kw * 4;
#pragma unroll
    for (int mt = 0; mt < 4; ++mt) {
#pragma unroll
      for (int nt = 0; nt < 2; ++nt) {
        int c3 = wv * 32 + nt * 16 + lcol;
        float4 v;
        v.x = acc[mt][nt][0]; v.y = acc[mt][nt][1];
        v.z = acc[mt][nt][2]; v.w = acc[mt][nt][3];
        *(float4*)(ob + (size_t)c3 * 32768 + mt * 1024 + lq * 32) = v;
      }
    }
  }
}

extern "C" void kernel_launch(void* const* d_in, const int* in_sizes, int n_in,
                              void* d_out, int out_size, void* d_ws, size_t ws_size,
                              hipStream_t stream) {
  const float* x = (const float*)d_in[0];
  const float* wq = (const float*)d_in[1];
  const float* wp = (const float*)d_in[2];
  float* out = (float*)d_out;
  f16* wq_h = (f16*)d_ws;            // 768*256 fp16
  f16* wp_h = wq_h + 768 * 256;      // 256*256 fp16  (total 512 KB of d_ws)

  (void)hipFuncSetAttribute((const void*)win_attn_k,
                            hipFuncAttributeMaxDynamicSharedMemorySize, SMEM_TOTAL);

  cvt_weights_k<<<1024, 256, 0, stream>>>(wq, wp, wq_h, wp_h);
  win_attn_k<<<2048, 512, SMEM_TOTAL, stream>>>(x, wq_h, wp_h, out);
}

// Round 2
// 281.197 us; speedup vs baseline: 1.3875x; 1.3875x over previous
//
#include <hip/hip_runtime.h>

typedef _Float16 f16;
typedef f16 f16x4 __attribute__((ext_vector_type(4)));
typedef f16 f16x8 __attribute__((ext_vector_type(8)));
typedef float f32x4 __attribute__((ext_vector_type(4)));

#define LDQ 68                 // qkvT row stride in halfs (64 tokens + 4 pad)
#define QKV_OFF 32768          // xw buffer: 64 rows * 512 B (swizzled, no pad)
#define QKV_BYTES (768 * LDQ * 2)        // 104448
#define SPART_OFF (QKV_OFF + QKV_BYTES)  // 137216
#define SPART_BYTES (32 * 64 * 4)        // 8192
#define SMEM_TOTAL (SPART_OFF + SPART_BYTES)  // 145408

// d_ws layout
#define WQH_OFF 0
#define WPH_OFF (768 * 256 * 2)                  // 393216 B
#define XW_OFF  (WPH_OFF + 256 * 256 * 2)        // 524288 B
#define O2_OFF  (XW_OFF + 2048 * 16384 * 2)      // + 67108864
#define WS_NEED ((size_t)O2_OFF + 2048 * 16384 * 2)

// fp32 -> fp16 weight conversion (w_qkv 768x256, w_proj 256x256)
__global__ __launch_bounds__(256) void cvt_weights_k(
    const float* __restrict__ wq, const float* __restrict__ wp,
    f16* __restrict__ wq_h, f16* __restrict__ wp_h) {
  int idx = blockIdx.x * 256 + threadIdx.x;  // grid covers 262144
  if (idx < 768 * 256) {
    wq_h[idx] = (f16)wq[idx];
  } else {
    int r = idx - 768 * 256;
    wp_h[r] = (f16)wp[r];
  }
}

// XOR-swizzled address into the xw/out2 LDS tile: row stride 512 B,
// byte^=((row&7)<<4) makes ds_read_b128 column-slices bank-conflict-free (T2).
__device__ __forceinline__ char* xwp(char* s, int row, int colbyte) {
  return s + row * 512 + (colbyte ^ ((row & 7) << 4));
}

// ---- K1: gather/transpose x (fp32, strided) -> xw_all (fp16, per-window
// contiguous, PRE-SWIZZLED so K2 can global_load_lds it linearly).
// Thread (g, c, a, bb) reads one full 32-float k-row (128 B contiguous) and
// writes one f16x4 per window (8 B), 2 KB contiguous per block per window.
__global__ __launch_bounds__(256) void gather_k(const float* __restrict__ x,
                                                f16* __restrict__ xw_all) {
  const int g = blockIdx.x >> 4, cb = blockIdx.x & 15;
  const int b = g >> 6, iw = (g >> 3) & 7, jw = g & 7;
  const int tid = threadIdx.x;
  const int c = cb * 16 + (tid >> 4), a = (tid >> 2) & 3, bb = tid & 3;
  const float* src = x + (size_t)b * 8388608 + (size_t)c * 32768 +
                     (iw * 4 + a) * 1024 + (jw * 4 + bb) * 32;
  const int t = c >> 2;
  const int c2b = (c & 3) * 128 + a * 32 + bb * 8;      // byte col within row
  const int byt = t * 512 + (c2b ^ ((t & 7) << 4));     // swizzled byte addr
  char* wbase = (char*)(xw_all + (size_t)(g << 3) * 16384) + byt;
#pragma unroll
  for (int kw = 0; kw < 8; ++kw) {
    float4 v = *(const float4*)(src + kw * 4);
    f16x4 h;
    h[0] = (f16)v.x; h[1] = (f16)v.y; h[2] = (f16)v.z; h[3] = (f16)v.w;
    *(f16x4*)(wbase + kw * 32768) = h;
  }
}

// ---- K3: scatter o2T (fp16, per-window contiguous [c3][t]) -> out (fp32).
// Thread (g, c3, a, bb) reads 8B per window, writes one full 128 B k-row.
__global__ __launch_bounds__(256) void scatter_k(const f16* __restrict__ o2T,
                                                 float* __restrict__ out) {
  const int g = blockIdx.x >> 4, cb = blockIdx.x & 15;
  const int b = g >> 6, iw = (g >> 3) & 7, jw = g & 7;
  const int tid = threadIdx.x;
  const int c3 = cb * 16 + (tid >> 4), a = (tid >> 2) & 3, bb = tid & 3;
  const f16* rbase = o2T + (size_t)(g << 3) * 16384 + c3 * 64 + a * 16 + bb * 4;
  float* dst = out + (size_t)b * 8388608 + (size_t)c3 * 32768 +
               (iw * 4 + a) * 1024 + (jw * 4 + bb) * 32;
#pragma unroll
  for (int kw = 0; kw < 8; ++kw) {
    f16x4 h = *(const f16x4*)(rbase + kw * 16384);
    float4 v;
    v.x = (float)h[0]; v.y = (float)h[1]; v.z = (float)h[2]; v.w = (float)h[3];
    *(float4*)(dst + kw * 4) = v;
  }
}

// ---- K2: per-window fused qkv-GEMM + head-cross attention + proj-GEMM ----
__global__ __launch_bounds__(512) void win_attn_k(
    const f16* __restrict__ xw_all, const f16* __restrict__ wq_h,
    const f16* __restrict__ wp_h, f16* __restrict__ o2T) {
  extern __shared__ char smem[];
  f16* qkvT = (f16*)(smem + QKV_OFF);     // [768 features][68] (64 tokens + pad)
  float* spart = (float*)(smem + SPART_OFF);  // [dh*4+h][g][64 tokens] f32

  const int tid = threadIdx.x;
  const int wi = blockIdx.x;  // window id == xw_all/o2T block index
  const int wv = tid >> 6, lane = tid & 63;
  const int lcol = lane & 15, lq = lane >> 4;

  // ---- Phase 1: 32 KB pre-swizzled xw -> LDS, direct-to-LDS loads ----
  {
    const char* gsrc =
        (const char*)(xw_all + (size_t)wi * 16384) + wv * 4096 + lane * 16;
#pragma unroll
    for (int i = 0; i < 4; ++i)
      __builtin_amdgcn_global_load_lds(
          (const __attribute__((address_space(1))) void*)(gsrc + i * 1024),
          (__attribute__((address_space(3))) void*)(smem + wv * 4096 + i * 1024),
          16, 0, 0);
  }
  __syncthreads();

  // ---- Phase 2: GEMM1 qkv[64x768] = xw[64x256] @ w_qkv^T, wave = 96-col slice ----
  for (int nc = 0; nc < 2; ++nc) {
    const int ncb = wv * 96 + nc * 48;
    f32x4 acc[4][3] = {};
    for (int kt = 0; kt < 8; ++kt) {
      f16x8 afr[4];
#pragma unroll
      for (int mt = 0; mt < 4; ++mt) {
        int row = mt * 16 + lcol;
        afr[mt] = *(const f16x8*)xwp(smem, row, kt * 64 + lq * 16);
      }
#pragma unroll
      for (int nt = 0; nt < 3; ++nt) {
        f16x8 bfr = *(const f16x8*)(wq_h + (ncb + nt * 16 + lcol) * 256 + kt * 32 + lq * 8);
#pragma unroll
        for (int mt = 0; mt < 4; ++mt)
          acc[mt][nt] = __builtin_amdgcn_mfma_f32_16x16x32_f16(afr[mt], bfr, acc[mt][nt], 0, 0, 0);
      }
    }
    // D layout: col = lane&15 (feature), row = lq*4 + r (token). Store transposed.
#pragma unroll
    for (int mt = 0; mt < 4; ++mt)
#pragma unroll
      for (int nt = 0; nt < 3; ++nt) {
        f16x4 hv;
        hv[0] = (f16)acc[mt][nt][0]; hv[1] = (f16)acc[mt][nt][1];
        hv[2] = (f16)acc[mt][nt][2]; hv[3] = (f16)acc[mt][nt][3];
        *(f16x4*)(qkvT + (ncb + nt * 16 + lcol) * LDQ + mt * 16 + lq * 4) = hv;
      }
  }
  __syncthreads();

  // ---- Phase 3a: S partials. wave = (h = wv&3, dh = wv>>2), lane = token t ----
  {
    const int h = wv & 3, dh = wv >> 2, t = lane;
    float qreg[32];
#pragma unroll
    for (int dd = 0; dd < 32; ++dd)
      qreg[dd] = (float)qkvT[(h * 64 + dh * 32 + dd) * LDQ + t];
#pragma unroll
    for (int g = 0; g < 4; ++g) {
      float s = 0.f;
#pragma unroll
      for (int dd = 0; dd < 32; ++dd)
        s += qreg[dd] * (float)qkvT[(256 + g * 64 + dh * 32 + dd) * LDQ + t];
      spart[((dh * 4 + h) * 4 + g) * 64 + t] = s;
    }
  }
  __syncthreads();

  // ---- Phase 3b: clip+softmax over g (4 heads), then O = P @ V (d-half per wave) ----
  {
    const int h = wv & 3, dh = wv >> 2, t = lane;
    float P[4];
    float mx = -1e30f;
#pragma unroll
    for (int g = 0; g < 4; ++g) {
      float s = spart[(h * 4 + g) * 64 + t] + spart[((4 + h) * 4 + g) * 64 + t];
      s *= 0.125f;                       // SCALE = 64^-0.5
      s = fminf(fmaxf(s, -10.f), 10.f);  // clip BEFORE softmax (reference order)
      P[g] = s;
      mx = fmaxf(mx, s);
    }
    float sum = 0.f;
#pragma unroll
    for (int g = 0; g < 4; ++g) { P[g] = __expf(P[g] - mx); sum += P[g]; }
    float inv = 1.f / sum;
#pragma unroll
    for (int g = 0; g < 4; ++g) P[g] *= inv;

    // out2[t2][c2]: t2 = h*16 + (t>>2), c2 = (t&3)*64 + d  (reuse xw LDS buffer)
    const int row = h * 16 + (t >> 2);
    const int cb0 = (t & 3) * 128 + dh * 64;
#pragma unroll
    for (int db = 0; db < 32; db += 8) {
      f16x8 hv;
#pragma unroll
      for (int u = 0; u < 8; ++u) {
        int d = dh * 32 + db + u;
        float o = 0.f;
#pragma unroll
        for (int g = 0; g < 4; ++g)
          o += P[g] * (float)qkvT[(512 + g * 64 + d) * LDQ + t];
        hv[u] = (f16)o;
      }
      *(f16x8*)xwp(smem, row, cb0 + db * 2) = hv;
    }
  }
  __syncthreads();

  // ---- Phase 4: GEMM2 final[64x256] = out2 @ w_proj^T, wave = 32-col slice ----
  {
    f32x4 acc[4][2] = {};
    for (int kt = 0; kt < 8; ++kt) {
      f16x8 afr[4];
#pragma unroll
      for (int mt = 0; mt < 4; ++mt)
        afr[mt] = *(const f16x8*)xwp(smem, mt * 16 + lcol, kt * 64 + lq * 16);
#pragma unroll
      for (int nt = 0; nt < 2; ++nt) {
        f16x8 bfr = *(const f16x8*)(wp_h + (wv * 32 + nt * 16 + lcol) * 256 + kt * 32 + lq * 8);
#pragma unroll
        for (int mt = 0; mt < 4; ++mt)
          acc[mt][nt] = __builtin_amdgcn_mfma_f32_16x16x32_f16(afr[mt], bfr, acc[mt][nt], 0, 0, 0);
      }
    }
    // D: col = c3 (feature), row = token t = mt*16 + lq*4 + r.
    // Write fp16 o2T[win][c3][t]: contiguous per window, full-line in L2.
    f16* ob = o2T + (size_t)wi * 16384;
#pragma unroll
    for (int mt = 0; mt < 4; ++mt) {
#pragma unroll
      for (int nt = 0; nt < 2; ++nt) {
        int c3 = wv * 32 + nt * 16 + lcol;
        f16x4 hv;
        hv[0] = (f16)acc[mt][nt][0]; hv[1] = (f16)acc[mt][nt][1];
        hv[2] = (f16)acc[mt][nt][2]; hv[3] = (f16)acc[mt][nt][3];
        *(f16x4*)(ob + c3 * 64 + mt * 16 + lq * 4) = hv;
      }
    }
  }
}

// ---- Fallback: round-1 fused kernel (used only if ws_size < WS_NEED) ----
__global__ __launch_bounds__(512) void win_attn_fused_k(
    const float* __restrict__ x, const f16* __restrict__ wq_h,
    const f16* __restrict__ wp_h, float* __restrict__ out) {
  extern __shared__ char smem[];
  f16* qkvT = (f16*)(smem + QKV_OFF);
  float* spart = (float*)(smem + SPART_OFF);

  const int tid = threadIdx.x;
  const int wi = blockIdx.x;
  const int kw = wi & 7, jw = (wi >> 3) & 7, iw = (wi >> 6) & 7, bw = wi >> 9;
  const float* xb = x + (size_t)bw * 8388608 + iw * 4096 + jw * 128 + kw * 4;

#pragma unroll
  for (int it = 0; it < 8; ++it) {
    int idx = it * 512 + tid;
    int c = idx >> 4, a = (idx >> 2) & 3, bb = idx & 3;
    float4 v = *(const float4*)(xb + (size_t)c * 32768 + a * 1024 + bb * 32);
    f16x4 h;
    h[0] = (f16)v.x; h[1] = (f16)v.y; h[2] = (f16)v.z; h[3] = (f16)v.w;
    *(f16x4*)xwp(smem, c >> 2, (c & 3) * 128 + a * 32 + bb * 8) = h;
  }
  __syncthreads();

  const int wv = tid >> 6, lane = tid & 63;
  const int lcol = lane & 15, lq = lane >> 4;

  for (int nc = 0; nc < 2; ++nc) {
    const int ncb = wv * 96 + nc * 48;
    f32x4 acc[4][3] = {};
    for (int kt = 0; kt < 8; ++kt) {
      f16x8 afr[4];
#pragma unroll
      for (int mt = 0; mt < 4; ++mt)
        afr[mt] = *(const f16x8*)xwp(smem, mt * 16 + lcol, kt * 64 + lq * 16);
#pragma unroll
      for (int nt = 0; nt < 3; ++nt) {
        f16x8 bfr = *(const f16x8*)(wq_h + (ncb + nt * 16 + lcol) * 256 + kt * 32 + lq * 8);
#pragma unroll
        for (int mt = 0; mt < 4; ++mt)
          acc[mt][nt] = __builtin_amdgcn_mfma_f32_16x16x32_f16(afr[mt], bfr, acc[mt][nt], 0, 0, 0);
      }
    }
#pragma unroll
    for (int mt = 0; mt < 4; ++mt)
#pragma unroll
      for (int nt = 0; nt < 3; ++nt) {
        f16x4 hv;
        hv[0] = (f16)acc[mt][nt][0]; hv[1] = (f16)acc[mt][nt][1];
        hv[2] = (f16)acc[mt][nt][2]; hv[3] = (f16)acc[mt][nt][3];
        *(f16x4*)(qkvT + (ncb + nt * 16 + lcol) * LDQ + mt * 16 + lq * 4) = hv;
      }
  }
  __syncthreads();

  {
    const int h = wv & 3, dh = wv >> 2, t = lane;
    float qreg[32];
#pragma unroll
    for (int dd = 0; dd < 32; ++dd)
      qreg[dd] = (float)qkvT[(h * 64 + dh * 32 + dd) * LDQ + t];
#pragma unroll
    for (int g = 0; g < 4; ++g) {
      float s = 0.f;
#pragma unroll
      for (int dd = 0; dd < 32; ++dd)
        s += qreg[dd] * (float)qkvT[(256 + g * 64 + dh * 32 + dd) * LDQ + t];
      spart[((dh * 4 + h) * 4 + g) * 64 + t] = s;
    }
  }
  __syncthreads();

  {
    const int h = wv & 3, dh = wv >> 2, t = lane;
    float P[4];
    float mx = -1e30f;
#pragma unroll
    for (int g = 0; g < 4; ++g) {
      float s = spart[(h * 4 + g) * 64 + t] + spart[((4 + h) * 4 + g) * 64 + t];
      s *= 0.125f;
      s = fminf(fmaxf(s, -10.f), 10.f);
      P[g] = s;
      mx = fmaxf(mx, s);
    }
    float sum = 0.f;
#pragma unroll
    for (int g = 0; g < 4; ++g) { P[g] = __expf(P[g] - mx); sum += P[g]; }
    float inv = 1.f / sum;
#pragma unroll
    for (int g = 0; g < 4; ++g) P[g] *= inv;

    const int row = h * 16 + (t >> 2);
    const int cb0 = (t & 3) * 128 + dh * 64;
#pragma unroll
    for (int db = 0; db < 32; db += 8) {
      f16x8 hv;
#pragma unroll
      for (int u = 0; u < 8; ++u) {
        int d = dh * 32 + db + u;
        float o = 0.f;
#pragma unroll
        for (int g = 0; g < 4; ++g)
          o += P[g] * (float)qkvT[(512 + g * 64 + d) * LDQ + t];
        hv[u] = (f16)o;
      }
      *(f16x8*)xwp(smem, row, cb0 + db * 2) = hv;
    }
  }
  __syncthreads();

  {
    f32x4 acc[4][2] = {};
    for (int kt = 0; kt < 8; ++kt) {
      f16x8 afr[4];
#pragma unroll
      for (int mt = 0; mt < 4; ++mt)
        afr[mt] = *(const f16x8*)xwp(smem, mt * 16 + lcol, kt * 64 + lq * 16);
#pragma unroll
      for (int nt = 0; nt < 2; ++nt) {
        f16x8 bfr = *(const f16x8*)(wp_h + (wv * 32 + nt * 16 + lcol) * 256 + kt * 32 + lq * 8);
#pragma unroll
        for (int mt = 0; mt < 4; ++mt)
          acc[mt][nt] = __builtin_amdgcn_mfma_f32_16x16x32_f16(afr[mt], bfr, acc[mt][nt], 0, 0, 0);
      }
    }
    float* ob = out + (size_t)bw * 8388608 + iw * 4096 + jw * 128 + kw * 4;
#pragma unroll
    for (int mt = 0; mt < 4; ++mt) {
#pragma unroll
      for (int nt = 0; nt < 2; ++nt) {
        int c3 = wv * 32 + nt * 16 + lcol;
        float4 v;
        v.x = acc[mt][nt][0]; v.y = acc[mt][nt][1];
        v.z = acc[mt][nt][2]; v.w = acc[mt][nt][3];
        *(float4*)(ob + (size_t)c3 * 32768 + mt * 1024 + lq * 32) = v;
      }
    }
  }
}

extern "C" void kernel_launch(void* const* d_in, const int* in_sizes, int n_in,
                              void* d_out, int out_size, void* d_ws, size_t ws_size,
                              hipStream_t stream) {
  const float* x = (const float*)d_in[0];
  const float* wq = (const float*)d_in[1];
  const float* wp = (const float*)d_in[2];
  float* out = (float*)d_out;
  char* ws = (char*)d_ws;
  f16* wq_h = (f16*)(ws + WQH_OFF);
  f16* wp_h = (f16*)(ws + WPH_OFF);

  cvt_weights_k<<<1024, 256, 0, stream>>>(wq, wp, wq_h, wp_h);

  if (ws_size >= WS_NEED) {
    f16* xw_all = (f16*)(ws + XW_OFF);
    f16* o2T = (f16*)(ws + O2_OFF);
    (void)hipFuncSetAttribute((const void*)win_attn_k,
                              hipFuncAttributeMaxDynamicSharedMemorySize, SMEM_TOTAL);
    gather_k<<<4096, 256, 0, stream>>>(x, xw_all);
    win_attn_k<<<2048, 512, SMEM_TOTAL, stream>>>(xw_all, wq_h, wp_h, o2T);
    scatter_k<<<4096, 256, 0, stream>>>(o2T, out);
  } else {
    (void)hipFuncSetAttribute((const void*)win_attn_fused_k,
                              hipFuncAttributeMaxDynamicSharedMemorySize, SMEM_TOTAL);
    win_attn_fused_k<<<2048, 512, SMEM_TOTAL, stream>>>(x, wq_h, wp_h, out);
  }
}